// Round 6
// baseline (101.299 us; speedup 1.0000x reference)
//
#include <hip/hip_runtime.h>

// ---- problem constants -----------------------------------------------------
#define NBATCH 64          // 4*16 collapsed
#define M_DIM  1024
#define K_DIM  256
#define N_DIM  1024

typedef __attribute__((ext_vector_type(4)))  int   i32x4;
typedef __attribute__((ext_vector_type(4)))  float f32x4;

union Pack16 { char c[16]; i32x4 i; };

// exact reference semantics: IEEE fp32 divide + rintf (round-half-even) + clip
__device__ __forceinline__ float quant4f(float v, float clip) {
    return fminf(fmaxf(rintf(v / clip), -8.0f), 7.0f);
}

// ---- pass 1: fused quantization --------------------------------------------
// blocks 0..4095   : quantize x -> qx i8 (straight copy, 16 elem/thread)
// blocks 4096..8191: quantize+transpose y -> qyT blocked [b][kb][n][64] i8
//                    (64x64 LDS tiles; phase-2 writes 4KB contiguous per wave)
__global__ __launch_bounds__(256) void quant_kernel(
        const float* __restrict__ x, const float* __restrict__ y,
        const float* __restrict__ xclip_p, const float* __restrict__ yclip_p,
        char* __restrict__ qx, char* __restrict__ qyT) {
    __shared__ float tile[64][65];            // +1 pad: <=2-way banks both phases
    const int bid = blockIdx.x;
    const int tid = threadIdx.x;

    if (bid < 4096) {                         // ---- x path ----
        const float clip = xclip_p[0];
        const int idx = (bid * 256 + tid) * 16;
        Pack16 o;
#pragma unroll
        for (int c = 0; c < 4; ++c) {
            f32x4 v = *(const f32x4*)(x + idx + c * 4);
#pragma unroll
            for (int j = 0; j < 4; ++j)
                o.c[c * 4 + j] = (char)(int)quant4f(v[j], clip);
        }
        *(i32x4*)(qx + idx) = o.i;
    } else {                                  // ---- y path ----
        const float clip = yclip_p[0];
        const int b2 = bid - 4096;
        const int n0 = (b2 & 15) * 64;
        const int kb = (b2 >> 4) & 3;         // k block 0..3
        const int k0 = kb * 64;
        const int b  = b2 >> 6;
        const float* yb = y + (size_t)b * K_DIM * N_DIM;
        const int kl = tid >> 4;              // 0..15
        const int nq = (tid & 15) * 4;        // 0..60
#pragma unroll
        for (int i = 0; i < 4; ++i) {         // float4 loads, 256B/row-segment
            f32x4 v = *(const f32x4*)(yb + (size_t)(k0 + kl + i * 16) * N_DIM + n0 + nq);
#pragma unroll
            for (int j = 0; j < 4; ++j)
                tile[kl + i * 16][nq + j] = quant4f(v[j], clip);
        }
        __syncthreads();
        // blocked layout: qyT[((b*4+kb)*1024 + n)*64 + kk]
        // thread tid: row nl, 16B chunk kc -> wave covers 4KB contiguous
        char* ob = qyT + ((size_t)b * 4 + kb) * 1024 * 64;
        const int nl = tid >> 2;              // 0..63
        const int kc = (tid & 3) * 16;        // 0,16,32,48
        Pack16 o;
#pragma unroll
        for (int j = 0; j < 16; ++j)
            o.c[j] = (char)(int)tile[kc + j][nl];
        *(i32x4*)(ob + (size_t)(n0 + nl) * 64 + kc) = o.i;
    }
}

// ---- pass 2: batched i8 MFMA GEMM, double-buffered K-loop ------------------
// A = qx[b] MxK row-major i8, B = qyT blocked [b][kb][n][64] i8, C = MxN f32.
// 128x128 tile, BK=64, 4 waves (2x2), mfma_i32_16x16x64_i8.
// Staging swizzle (rule #21): linear LDS dest + inverse-swizzled GLOBAL source
// (slot ^= row&3) + swizzled LDS read -> fragment reads 4-way banks max.
#define GLD16(gp, lp) __builtin_amdgcn_global_load_lds(                         \
    (const __attribute__((address_space(1))) void*)(gp),                        \
    (__attribute__((address_space(3))) void*)(lp), 16, 0, 0)

__global__ __launch_bounds__(256, 4) void q4_gemm_kernel(
        const char* __restrict__ qx,
        const char* __restrict__ qyT,
        const float* __restrict__ xclip_p, const float* __restrict__ yclip_p,
        float* __restrict__ out) {
    // XCD-chunked swizzle: 4096 wgs / 8 XCDs -> 8 consecutive batches per XCD
    const int p = blockIdx.x;
    const int l = (p & 7) * 512 + (p >> 3);
    const int b  = l >> 6;                    // batch 0..63
    const int t  = l & 63;
    const int br = t >> 3;                    // tile row 0..7
    const int bc = t & 7;                     // tile col 0..7

    // double-buffered staging: buf k: A at smem+k*16384, B at +8192 (32KB)
    // epilogue overlays smem as padded C-stage [32][132] f32 (16.9KB)
    __shared__ __align__(16) char smem[32768];
    float (*Cst)[132] = (float (*)[132])smem;

    const int tid  = threadIdx.x;
    const int lane = tid & 63;
    const int wid  = tid >> 6;
    const int wr   = wid >> 1;                // wave row 0..1
    const int wc   = wid & 1;                 // wave col 0..1

    const char* Abase = qx  + (size_t)b * M_DIM * K_DIM + (size_t)br * 128 * K_DIM;
    const char* Bbase = qyT + (size_t)b * 4 * 65536 + (size_t)bc * 128 * 64;

    // per-thread staging coordinates (2 chunks of 16B for A, 2 for B)
    const int row0  = tid >> 2;               // chunks 0..255  -> rows 0..63
    const int row1  = (tid + 256) >> 2;       // chunks 256..511-> rows 64..127
    const int slot  = tid & 3;
    const int ks0   = (slot ^ (row0 & 3)) * 16;
    const int ks1   = (slot ^ (row1 & 3)) * 16;

    i32x4 acc[4][4] = {};

    const int lrow15 = lane & 15;
    const int s      = lane >> 4;             // k-slot 0..3 (16B each)

    // ---- prologue: stage K-step 0 into buf 0 ----
    {
        char* As = smem; char* Bs = smem + 8192;
        GLD16(Abase + (size_t)row0 * K_DIM + ks0, As + tid * 16);
        GLD16(Bbase + (size_t)row0 * 64 + ks0, Bs + tid * 16);
        GLD16(Abase + (size_t)row1 * K_DIM + ks1, As + (tid + 256) * 16);
        GLD16(Bbase + (size_t)row1 * 64 + ks1, Bs + (tid + 256) * 16);
    }
    __syncthreads();                          // vmcnt(0) drain + barrier

#pragma unroll
    for (int kt = 0; kt < 4; ++kt) {          // 4 K-steps of 64
        char* As = smem + (kt & 1) * 16384;
        char* Bs = As + 8192;
        // issue next K-step's loads into the other buffer (overlaps compute)
        if (kt < 3) {
            const int ka = (kt + 1) * 64;               // A k-offset (bytes)
            const size_t kbb = (size_t)(kt + 1) * 65536; // B block offset
            char* An = smem + ((kt + 1) & 1) * 16384;
            char* Bn = An + 8192;
            GLD16(Abase + (size_t)row0 * K_DIM + ka + ks0, An + tid * 16);
            GLD16(Bbase + kbb + (size_t)row0 * 64 + ks0, Bn + tid * 16);
            GLD16(Abase + (size_t)row1 * K_DIM + ka + ks1, An + (tid + 256) * 16);
            GLD16(Bbase + kbb + (size_t)row1 * 64 + ks1, Bn + (tid + 256) * 16);
        }

        i32x4 af[4], bf[4];
#pragma unroll
        for (int m = 0; m < 4; ++m) {
            int row = wr * 64 + m * 16 + lrow15;
            af[m] = *(const i32x4*)(As + row * 64 + ((s ^ (row & 3)) * 16));
        }
#pragma unroll
        for (int n = 0; n < 4; ++n) {
            int row = wc * 64 + n * 16 + lrow15;
            bf[n] = *(const i32x4*)(Bs + row * 64 + ((s ^ (row & 3)) * 16));
        }
#pragma unroll
        for (int m = 0; m < 4; ++m)
#pragma unroll
            for (int n = 0; n < 4; ++n)
                acc[m][n] = __builtin_amdgcn_mfma_i32_16x16x64_i8(
                                af[m], bf[n], acc[m][n], 0, 0, 0);
        // one barrier per step: drains this wave's vmcnt (next buf ready) and
        // guarantees all waves finished reading the current buf before reuse.
        __syncthreads();
    }

    // ---- epilogue: shared LDS-bounce -> full-line float4 stores ----
    // C/D layout col=lane&15, row=(lane>>4)*4+j (dtype-independent)
    const float scale = xclip_p[0] * yclip_p[0];
    const size_t cb = (size_t)b * M_DIM * N_DIM
                    + (size_t)(br * 128) * N_DIM + bc * 128;
    const int rsub = (lane >> 4) * 4;
    const int rdr  = tid >> 3;                // 0..31 read row
    const int cdw0 = (tid & 7) * 4;           // 0..28 col dword base

#pragma unroll
    for (int m = 0; m < 4; ++m) {
        // write 32x128 quadrant (rows wr*16+0..15 per wave) into padded LDS
#pragma unroll
        for (int n = 0; n < 4; ++n)
#pragma unroll
            for (int j = 0; j < 4; ++j)
                Cst[wr * 16 + rsub + j][wc * 64 + n * 16 + lrow15] =
                    (float)acc[m][n][j] * scale;
        __syncthreads();
        // read row-major, store float4: 8 lanes = 128B contiguous line.
        // plain stores (no nt): L2-mediated full-line writebacks burst better
        const int grow = (rdr >> 4) * 64 + m * 16 + (rdr & 15);
#pragma unroll
        for (int i = 0; i < 4; ++i) {
            f32x4 v = *(const f32x4*)&Cst[rdr][cdw0 + i * 32];
            *(f32x4*)(out + cb + (size_t)grow * N_DIM + cdw0 + i * 32) = v;
        }
        __syncthreads();                      // before next quadrant overwrite
    }
}

// ---- launcher --------------------------------------------------------------
extern "C" void kernel_launch(void* const* d_in, const int* in_sizes, int n_in,
                              void* d_out, int out_size, void* d_ws, size_t ws_size,
                              hipStream_t stream) {
    const float* x     = (const float*)d_in[0];   // [4,16,1024,256]
    const float* y     = (const float*)d_in[1];   // [4,16,256,1024]
    const float* xclip = (const float*)d_in[2];   // scalar
    const float* yclip = (const float*)d_in[3];   // scalar
    float* out = (float*)d_out;                   // [4,16,1024,1024] fp32

    // workspace: qx i8 16MB + qyT i8 16MB = 32MB
    char* qx  = (char*)d_ws;
    char* qyT = qx + (size_t)NBATCH * M_DIM * K_DIM;

    // fused quant: 4096 x-blocks + 4096 y-tile blocks
    quant_kernel<<<8192, 256, 0, stream>>>(x, y, xclip, yclip, qx, qyT);
    // GEMM: 64 batches x 8x8 tiles = 4096 blocks
    q4_gemm_kernel<<<4096, 256, 0, stream>>>(qx, qyT, xclip, yclip, out);
}

// Round 7
// 79.760 us; speedup vs baseline: 1.2700x; 1.2700x over previous
//
#include <hip/hip_runtime.h>

// ---- problem constants -----------------------------------------------------
#define NBATCH 64          // 4*16 collapsed
#define M_DIM  1024
#define K_DIM  256
#define N_DIM  1024

typedef __attribute__((ext_vector_type(4)))  int   i32x4;
typedef __attribute__((ext_vector_type(4)))  float f32x4;

union Pack16 { char c[16]; i32x4 i; };

// exact reference semantics: IEEE fp32 divide + rintf (round-half-even) + clip
__device__ __forceinline__ float quant4f(float v, float clip) {
    return fminf(fmaxf(rintf(v / clip), -8.0f), 7.0f);
}

// ---- pass 1: fused quantization --------------------------------------------
// blocks 0..4095   : quantize x -> qx i8 (straight copy, 16 elem/thread)
// blocks 4096..8191: quantize+transpose y -> qyT blocked [b][kb][n][64] i8
//                    (64x64 LDS tiles; phase-2 writes 4KB contiguous per wave)
__global__ __launch_bounds__(256) void quant_kernel(
        const float* __restrict__ x, const float* __restrict__ y,
        const float* __restrict__ xclip_p, const float* __restrict__ yclip_p,
        char* __restrict__ qx, char* __restrict__ qyT) {
    __shared__ float tile[64][65];            // +1 pad: <=2-way banks both phases
    const int bid = blockIdx.x;
    const int tid = threadIdx.x;

    if (bid < 4096) {                         // ---- x path ----
        const float clip = xclip_p[0];
        const int idx = (bid * 256 + tid) * 16;
        Pack16 o;
#pragma unroll
        for (int c = 0; c < 4; ++c) {
            f32x4 v = *(const f32x4*)(x + idx + c * 4);
#pragma unroll
            for (int j = 0; j < 4; ++j)
                o.c[c * 4 + j] = (char)(int)quant4f(v[j], clip);
        }
        *(i32x4*)(qx + idx) = o.i;
    } else {                                  // ---- y path ----
        const float clip = yclip_p[0];
        const int b2 = bid - 4096;
        const int n0 = (b2 & 15) * 64;
        const int kb = (b2 >> 4) & 3;         // k block 0..3
        const int k0 = kb * 64;
        const int b  = b2 >> 6;
        const float* yb = y + (size_t)b * K_DIM * N_DIM;
        const int kl = tid >> 4;              // 0..15
        const int nq = (tid & 15) * 4;        // 0..60
#pragma unroll
        for (int i = 0; i < 4; ++i) {         // float4 loads, 256B/row-segment
            f32x4 v = *(const f32x4*)(yb + (size_t)(k0 + kl + i * 16) * N_DIM + n0 + nq);
#pragma unroll
            for (int j = 0; j < 4; ++j)
                tile[kl + i * 16][nq + j] = quant4f(v[j], clip);
        }
        __syncthreads();
        // blocked layout: qyT[((b*4+kb)*1024 + n)*64 + kk]
        // thread tid: row nl, 16B chunk kc -> wave covers 4KB contiguous
        char* ob = qyT + ((size_t)b * 4 + kb) * 1024 * 64;
        const int nl = tid >> 2;              // 0..63
        const int kc = (tid & 3) * 16;        // 0,16,32,48
        Pack16 o;
#pragma unroll
        for (int j = 0; j < 16; ++j)
            o.c[j] = (char)(int)tile[kc + j][nl];
        *(i32x4*)(ob + (size_t)(n0 + nl) * 64 + kc) = o.i;
    }
}

// ---- pass 2: batched i8 MFMA GEMM, double-buffered K-loop ------------------
// A = qx[b] MxK row-major i8, B = qyT blocked [b][kb][n][64] i8, C = MxN f32.
// 128x128 tile, BK=64, 4 waves (2x2), mfma_i32_16x16x64_i8.
// Staging swizzle (rule #21): linear LDS dest + inverse-swizzled GLOBAL source
// (slot ^= row&3) + swizzled LDS read -> fragment reads 4-way banks max.
#define GLD16(gp, lp) __builtin_amdgcn_global_load_lds(                         \
    (const __attribute__((address_space(1))) void*)(gp),                        \
    (__attribute__((address_space(3))) void*)(lp), 16, 0, 0)

__global__ __launch_bounds__(256, 4) void q4_gemm_kernel(
        const char* __restrict__ qx,
        const char* __restrict__ qyT,
        const float* __restrict__ xclip_p, const float* __restrict__ yclip_p,
        float* __restrict__ out) {
    // XCD-chunked swizzle: 4096 wgs / 8 XCDs -> 8 consecutive batches per XCD
    const int p = blockIdx.x;
    const int l = (p & 7) * 512 + (p >> 3);
    const int b  = l >> 6;                    // batch 0..63
    const int t  = l & 63;
    const int br = t >> 3;                    // tile row 0..7
    const int bc = t & 7;                     // tile col 0..7

    // double-buffered staging: buf k: A at smem+k*16384, B at +8192 (32KB)
    // epilogue overlays smem as padded C-stage [32][132] f32 (16.9KB)
    __shared__ __align__(16) char smem[32768];
    float (*Cst)[132] = (float (*)[132])smem;

    const int tid  = threadIdx.x;
    const int lane = tid & 63;
    const int wid  = tid >> 6;
    const int wr   = wid >> 1;                // wave row 0..1
    const int wc   = wid & 1;                 // wave col 0..1

    const char* Abase = qx  + (size_t)b * M_DIM * K_DIM + (size_t)br * 128 * K_DIM;
    const char* Bbase = qyT + (size_t)b * 4 * 65536 + (size_t)bc * 128 * 64;

    // per-thread staging coordinates (2 chunks of 16B for A, 2 for B)
    const int row0  = tid >> 2;               // chunks 0..255  -> rows 0..63
    const int row1  = (tid + 256) >> 2;       // chunks 256..511-> rows 64..127
    const int slot  = tid & 3;
    const int ks0   = (slot ^ (row0 & 3)) * 16;
    const int ks1   = (slot ^ (row1 & 3)) * 16;

    i32x4 acc[4][4] = {};

    const int lrow15 = lane & 15;
    const int s      = lane >> 4;             // k-slot 0..3 (16B each)

    // ---- prologue: stage K-step 0 into buf 0 ----
    {
        char* As = smem; char* Bs = smem + 8192;
        GLD16(Abase + (size_t)row0 * K_DIM + ks0, As + tid * 16);
        GLD16(Bbase + (size_t)row0 * 64 + ks0, Bs + tid * 16);
        GLD16(Abase + (size_t)row1 * K_DIM + ks1, As + (tid + 256) * 16);
        GLD16(Bbase + (size_t)row1 * 64 + ks1, Bs + (tid + 256) * 16);
    }
    __syncthreads();                          // vmcnt(0) drain + barrier

#pragma unroll
    for (int kt = 0; kt < 4; ++kt) {          // 4 K-steps of 64
        char* As = smem + (kt & 1) * 16384;
        char* Bs = As + 8192;
        // issue next K-step's loads into the other buffer (overlaps compute)
        if (kt < 3) {
            const int ka = (kt + 1) * 64;               // A k-offset (bytes)
            const size_t kbb = (size_t)(kt + 1) * 65536; // B block offset
            char* An = smem + ((kt + 1) & 1) * 16384;
            char* Bn = An + 8192;
            GLD16(Abase + (size_t)row0 * K_DIM + ka + ks0, An + tid * 16);
            GLD16(Bbase + kbb + (size_t)row0 * 64 + ks0, Bn + tid * 16);
            GLD16(Abase + (size_t)row1 * K_DIM + ka + ks1, An + (tid + 256) * 16);
            GLD16(Bbase + kbb + (size_t)row1 * 64 + ks1, Bn + (tid + 256) * 16);
        }

        i32x4 af[4], bf[4];
#pragma unroll
        for (int m = 0; m < 4; ++m) {
            int row = wr * 64 + m * 16 + lrow15;
            af[m] = *(const i32x4*)(As + row * 64 + ((s ^ (row & 3)) * 16));
        }
#pragma unroll
        for (int n = 0; n < 4; ++n) {
            int row = wc * 64 + n * 16 + lrow15;
            bf[n] = *(const i32x4*)(Bs + row * 64 + ((s ^ (row & 3)) * 16));
        }
#pragma unroll
        for (int m = 0; m < 4; ++m)
#pragma unroll
            for (int n = 0; n < 4; ++n)
                acc[m][n] = __builtin_amdgcn_mfma_i32_16x16x64_i8(
                                af[m], bf[n], acc[m][n], 0, 0, 0);
        // one barrier per step: drains this wave's vmcnt (next buf ready) and
        // guarantees all waves finished reading the current buf before reuse.
        __syncthreads();
    }

    // ---- epilogue: shared LDS-bounce -> full-line float4 NT stores ----
    // C/D layout col=lane&15, row=(lane>>4)*4+j (dtype-independent).
    // nt is load-bearing (R4/R6 A/B: -21us): 256MB write-once stream must
    // bypass L2 or it evicts the operand tiles + adds writeback pressure.
    const float scale = xclip_p[0] * yclip_p[0];
    const size_t cb = (size_t)b * M_DIM * N_DIM
                    + (size_t)(br * 128) * N_DIM + bc * 128;
    const int rsub = (lane >> 4) * 4;
    const int rdr  = tid >> 3;                // 0..31 read row
    const int cdw0 = (tid & 7) * 4;           // 0..28 col dword base

#pragma unroll
    for (int m = 0; m < 4; ++m) {
        // write 32x128 quadrant (rows wr*16+0..15 per wave) into padded LDS
#pragma unroll
        for (int n = 0; n < 4; ++n)
#pragma unroll
            for (int j = 0; j < 4; ++j)
                Cst[wr * 16 + rsub + j][wc * 64 + n * 16 + lrow15] =
                    (float)acc[m][n][j] * scale;
        __syncthreads();
        // read row-major, store float4: 8 lanes = 128B contiguous line
        const int grow = (rdr >> 4) * 64 + m * 16 + (rdr & 15);
#pragma unroll
        for (int i = 0; i < 4; ++i) {
            f32x4 v = *(const f32x4*)&Cst[rdr][cdw0 + i * 32];
            __builtin_nontemporal_store(
                v, (f32x4*)(out + cb + (size_t)grow * N_DIM + cdw0 + i * 32));
        }
        __syncthreads();                      // before next quadrant overwrite
    }
}

// ---- launcher --------------------------------------------------------------
extern "C" void kernel_launch(void* const* d_in, const int* in_sizes, int n_in,
                              void* d_out, int out_size, void* d_ws, size_t ws_size,
                              hipStream_t stream) {
    const float* x     = (const float*)d_in[0];   // [4,16,1024,256]
    const float* y     = (const float*)d_in[1];   // [4,16,256,1024]
    const float* xclip = (const float*)d_in[2];   // scalar
    const float* yclip = (const float*)d_in[3];   // scalar
    float* out = (float*)d_out;                   // [4,16,1024,1024] fp32

    // workspace: qx i8 16MB + qyT i8 16MB = 32MB
    char* qx  = (char*)d_ws;
    char* qyT = qx + (size_t)NBATCH * M_DIM * K_DIM;

    // fused quant: 4096 x-blocks + 4096 y-tile blocks
    quant_kernel<<<8192, 256, 0, stream>>>(x, y, xclip, yclip, qx, qyT);
    // GEMM: 64 batches x 8x8 tiles = 4096 blocks
    q4_gemm_kernel<<<4096, 256, 0, stream>>>(qx, qyT, xclip, yclip, out);
}